// Round 7
// baseline (8376.299 us; speedup 1.0000x reference)
//
#include <hip/hip_runtime.h>
#include <hip/hip_bf16.h>
#include <stdint.h>

typedef __bf16 bf16x8 __attribute__((ext_vector_type(8)));
typedef float f32x4 __attribute__((ext_vector_type(4)));
typedef unsigned short u16;
typedef u16 u16x8 __attribute__((ext_vector_type(8)));

static constexpr int TL = 6, TB = 8, TS = 2048, TD = 1024, TDFF = 4096, TC = 100;
static constexpr int TM = TB * TS;  // 16384 tokens

__device__ __forceinline__ u16 f2b(float f) {
  union { float f; uint32_t u; } v; v.f = f;
  return (u16)((v.u + 0x7FFFu + ((v.u >> 16) & 1u)) >> 16);
}
__device__ __forceinline__ float b2f(u16 h) {
  union { uint32_t u; float f; } v; v.u = ((uint32_t)h) << 16;
  return v.f;
}

#define GLDS16(gp, lp) \
  __builtin_amdgcn_global_load_lds((__attribute__((address_space(1))) void*)(gp), \
                                   (__attribute__((address_space(3))) void*)(lp), 16, 0, 0)

__device__ __forceinline__ void sbar() { __builtin_amdgcn_s_barrier(); }
__device__ __forceinline__ void schedb() { __builtin_amdgcn_sched_barrier(0); }

// ---------------- elementwise ----------------
__global__ __launch_bounds__(256) void k_addpos(const float* __restrict__ x, const float* __restrict__ pos,
                                                u16* __restrict__ hb) {
  int idx = blockIdx.x * 256 + threadIdx.x;
  float4 xv = ((const float4*)x)[idx];
  float4 pv = ((const float4*)pos)[idx & (TD / 4 - 1)];
  ushort4 ob;
  ob.x = f2b(xv.x + pv.x); ob.y = f2b(xv.y + pv.y);
  ob.z = f2b(xv.z + pv.z); ob.w = f2b(xv.w + pv.w);
  ((ushort4*)hb)[idx] = ob;
}

__global__ __launch_bounds__(256) void k_decinit(const float* __restrict__ cq, u16* __restrict__ db) {
  int idx = blockIdx.x * 256 + threadIdx.x;
  float4 v = ((const float4*)cq)[idx & (TD / 4 - 1)];
  ushort4 ob; ob.x = f2b(v.x); ob.y = f2b(v.y); ob.z = f2b(v.z); ob.w = f2b(v.w);
  ((ushort4*)db)[idx] = ob;
}

// transpose + convert: W [K,N] f32 -> Wt [Npad,K] bf16 (rows N..Npad zero-filled)
__global__ void k_tcvt(const float* __restrict__ W, u16* __restrict__ Wt, int K, int N, int Npad) {
  __shared__ float tile[32][33];
  int bn = blockIdx.x * 32, bk = blockIdx.y * 32;
  int tx = threadIdx.x, ty = threadIdx.y;  // 32x8
  #pragma unroll
  for (int i = ty; i < 32; i += 8) {
    int k = bk + i, n = bn + tx;
    tile[i][tx] = (k < K && n < N) ? W[(size_t)k * N + n] : 0.f;
  }
  __syncthreads();
  #pragma unroll
  for (int i = ty; i < 32; i += 8) {
    int n = bn + i, k = bk + tx;
    if (n < Npad && k < K) Wt[(size_t)n * K + k] = (n < N) ? f2b(tile[tx][i]) : (u16)0;
  }
}

// merged transpose+convert for the four [D,D] attention weights (z = which)
__global__ void k_tcvt4(const float* __restrict__ w0, const float* __restrict__ w1,
                        const float* __restrict__ w2, const float* __restrict__ w3,
                        u16* __restrict__ Wt) {
  __shared__ float tile[32][33];
  const float* W = (blockIdx.z == 0) ? w0 : (blockIdx.z == 1) ? w1 : (blockIdx.z == 2) ? w2 : w3;
  u16* O = Wt + (size_t)blockIdx.z * TD * TD;
  int bn = blockIdx.x * 32, bk = blockIdx.y * 32;
  int tx = threadIdx.x, ty = threadIdx.y;  // 32x8
  #pragma unroll
  for (int i = ty; i < 32; i += 8) tile[i][tx] = W[(size_t)(bk + i) * TD + bn + tx];
  __syncthreads();
  #pragma unroll
  for (int i = ty; i < 32; i += 8) O[(size_t)(bn + i) * TD + bk + tx] = f2b(tile[tx][i]);
}

// LayerNorm over D=1024: out = LN(a + b (+ bias)) * g + be ; bf16 in, bf16 out
template<bool HAS_BIAS>
__global__ __launch_bounds__(256) void k_ln(const u16* __restrict__ a, const u16* __restrict__ b,
                                            const float* __restrict__ bias,
                                            const float* __restrict__ g, const float* __restrict__ be,
                                            u16* __restrict__ outb) {
  int row = blockIdx.x, t = threadIdx.x;
  size_t base = (size_t)row * TD;
  ushort4 av = ((const ushort4*)(a + base))[t];
  ushort4 bv = ((const ushort4*)(b + base))[t];
  float xv[4];
  xv[0] = b2f(av.x) + b2f(bv.x);
  xv[1] = b2f(av.y) + b2f(bv.y);
  xv[2] = b2f(av.z) + b2f(bv.z);
  xv[3] = b2f(av.w) + b2f(bv.w);
  if (HAS_BIAS) {
    float4 bb = ((const float4*)bias)[t];
    xv[0] += bb.x; xv[1] += bb.y; xv[2] += bb.z; xv[3] += bb.w;
  }
  float s = xv[0] + xv[1] + xv[2] + xv[3];
  float q = xv[0] * xv[0] + xv[1] * xv[1] + xv[2] * xv[2] + xv[3] * xv[3];
  #pragma unroll
  for (int o = 32; o > 0; o >>= 1) { s += __shfl_down(s, o); q += __shfl_down(q, o); }
  __shared__ float ss[4], qs_[4];
  int wv = t >> 6;
  if ((t & 63) == 0) { ss[wv] = s; qs_[wv] = q; }
  __syncthreads();
  s = ss[0] + ss[1] + ss[2] + ss[3];
  q = qs_[0] + qs_[1] + qs_[2] + qs_[3];
  float m = s * (1.f / TD);
  float rs = rsqrtf(q * (1.f / TD) - m * m + 1e-5f);
  float4 gv = ((const float4*)g)[t];
  float4 bev = ((const float4*)be)[t];
  ushort4 ob;
  ob.x = f2b((xv[0] - m) * rs * gv.x + bev.x);
  ob.y = f2b((xv[1] - m) * rs * gv.y + bev.y);
  ob.z = f2b((xv[2] - m) * rs * gv.z + bev.z);
  ob.w = f2b((xv[3] - m) * rs * gv.w + bev.w);
  ((ushort4*)(outb + base))[t] = ob;
}

// per-token 16x16 head-mix "attention": one wave per token. Ob may alias Qb.
__global__ __launch_bounds__(256) void k_attn(const u16* __restrict__ Qb, const u16* __restrict__ Kb,
                                              const u16* __restrict__ Vb, u16* __restrict__ Ob) {
  constexpr int ST = 72;  // padded row stride (floats)
  __shared__ float sh[4][3][16 * ST];
  __shared__ float ps[4][16 * 17];
  const int wv = threadIdx.x >> 6, ln = threadIdx.x & 63;
  const size_t base = ((size_t)blockIdx.x * 4 + wv) * TD;
  float* qs = sh[wv][0];
  float* ks = sh[wv][1];
  float* vs = sh[wv][2];
  #pragma unroll
  for (int it = 0; it < 4; ++it) {
    const int e = it * 256 + ln * 4;
    const int li = (e >> 6) * ST + (e & 63);
    ushort4 qv = *(const ushort4*)(Qb + base + e);
    ushort4 kv = *(const ushort4*)(Kb + base + e);
    ushort4 vv = *(const ushort4*)(Vb + base + e);
    *(float4*)(qs + li) = make_float4(b2f(qv.x), b2f(qv.y), b2f(qv.z), b2f(qv.w));
    *(float4*)(ks + li) = make_float4(b2f(kv.x), b2f(kv.y), b2f(kv.z), b2f(kv.w));
    *(float4*)(vs + li) = make_float4(b2f(vv.x), b2f(vv.y), b2f(vv.z), b2f(vv.w));
  }
  __syncthreads();
  const int hi = ln >> 2, jg = ln & 3;
  float sc[4] = {0.f, 0.f, 0.f, 0.f};
  for (int d = 0; d < 64; ++d) {
    const float qv = qs[hi * ST + d];
    #pragma unroll
    for (int jj = 0; jj < 4; ++jj) sc[jj] += qv * ks[(jg * 4 + jj) * ST + d];
  }
  #pragma unroll
  for (int jj = 0; jj < 4; ++jj) sc[jj] *= 0.125f;  // 1/sqrt(64)
  float mx = fmaxf(fmaxf(sc[0], sc[1]), fmaxf(sc[2], sc[3]));
  mx = fmaxf(mx, __shfl_xor(mx, 1, 4));
  mx = fmaxf(mx, __shfl_xor(mx, 2, 4));
  float sum = 0.f;
  #pragma unroll
  for (int jj = 0; jj < 4; ++jj) { sc[jj] = __expf(sc[jj] - mx); sum += sc[jj]; }
  sum += __shfl_xor(sum, 1, 4);
  sum += __shfl_xor(sum, 2, 4);
  const float inv = 1.f / sum;
  #pragma unroll
  for (int jj = 0; jj < 4; ++jj) ps[wv][hi * 17 + jg * 4 + jj] = sc[jj] * inv;
  __syncthreads();
  float out[16];
  #pragma unroll
  for (int t = 0; t < 16; ++t) out[t] = 0.f;
  #pragma unroll
  for (int j = 0; j < 16; ++j) {
    const float pij = ps[wv][hi * 17 + j];
    #pragma unroll
    for (int t = 0; t < 16; ++t) out[t] += pij * vs[j * ST + jg * 16 + t];
  }
  u16* op = Ob + base + hi * 64 + jg * 16;
  #pragma unroll
  for (int t4 = 0; t4 < 4; ++t4) {
    ushort4 ob;
    ob.x = f2b(out[t4 * 4 + 0]); ob.y = f2b(out[t4 * 4 + 1]);
    ob.z = f2b(out[t4 * 4 + 2]); ob.w = f2b(out[t4 * 4 + 3]);
    *(ushort4*)(op + t4 * 4) = ob;
  }
}

// ============ 256x256 8-phase pipelined GEMM (T2+T3+T4+T5, NO XCD swizzle) ============
// C[M,Nn](bf16) = A[M,Kk](bf16) @ Bt[Nn,Kk](bf16)^T.  BK=64, 8 waves (2Mx4N),
// 128KB dbuf LDS, granule swizzle elem^=(row&7)<<3 on stage-source AND ds_read,
// counted vmcnt(6) once per K-tile, raw barriers, setprio, static parity unroll,
// running global pointers. XCD swizzle REMOVED: measured net-negative here
// (r3=6399us no-swz vs r6=7572us swz; FF1 fetch 147->188MB, write 128->206MB —
// L3-fit multi-kernel pipeline regime, m160 caveat).
// EPI 0: bf16 store (stride Nn). EPI 1: bias+relu -> bf16.
template<int EPI>
__global__ __launch_bounds__(512, 2) void k_gemm256(const u16* __restrict__ A, const u16* __restrict__ Bt,
                                                    u16* __restrict__ Cb, const float* __restrict__ bias,
                                                    int Nn, int Kk) {
  __shared__ __align__(16) u16 lds[67584];  // dbuf [A 16K | B 16K] u16; epilogue [256][264]
  const int t = threadIdx.x;
  const int wv = t >> 6, ln = t & 63;
  const int wm = wv >> 2, wn = wv & 3;
  const int bm = blockIdx.y * 256, bn = blockIdx.x * 256;

  const int srow = t >> 3;                            // staging row within 64-row quarter
  const int ssc = ((t & 7) * 8) ^ ((srow & 7) << 3);  // pre-swizzled source col
  const int fr = ln & 15;
  const int fk = (ln >> 4) * 8;
  const int fperm = (fr & 7) << 3;
  const int kc0 = fk ^ fperm;
  const int kc1 = (32 + fk) ^ fperm;
  const int arow = (wm * 128 + fr) * 64;
  const int brow = (wn * 64 + fr) * 64;
  const int ld0 = wv * 512;

  const size_t rowK = (size_t)Kk;
  const size_t row64 = rowK * 64;
  const u16* gA = A + (size_t)(bm + srow) * rowK + ssc;
  const u16* gB = Bt + (size_t)(bn + srow) * rowK + ssc;

  f32x4 acc[8][4] = {};

#define G2_(p0, c) do { GLDS16((p0), &lds[(c) + ld0]); GLDS16((p0) + row64, &lds[(c) + 4096 + ld0]); } while (0)
#define LA_(buf, m, ks) (*(const bf16x8*)&lds[(buf) * 32768 + arow + (m) * 1024 + ((ks) ? kc1 : kc0)])
#define LB_(buf, n, ks) (*(const bf16x8*)&lds[(buf) * 32768 + 16384 + brow + (n) * 1024 + ((ks) ? kc1 : kc0)])
#define MM_(a, b, c) __builtin_amdgcn_mfma_f32_16x16x32_bf16(a, b, c, 0, 0, 0)
#define ROW_(m, X0, X1) \
  acc[m][0] = MM_(X0, Bf00, acc[m][0]); acc[m][0] = MM_(X1, Bf01, acc[m][0]); \
  acc[m][1] = MM_(X0, Bf10, acc[m][1]); acc[m][1] = MM_(X1, Bf11, acc[m][1]); \
  acc[m][2] = MM_(X0, Bf20, acc[m][2]); acc[m][2] = MM_(X1, Bf21, acc[m][2]); \
  acc[m][3] = MM_(X0, Bf30, acc[m][3]); acc[m][3] = MM_(X1, Bf31, acc[m][3]);

  // 4 phases per K-tile; stage cadence: ph1 = (t+1).A1 -> buf Q, ph2/3/4 = (t+2).B0/B1/A0 -> buf P.
#define WIN_(P, Q, S1, S2, VM) do { \
    bf16x8 Bf00 = LB_(P,0,0), Bf01 = LB_(P,0,1), Bf10 = LB_(P,1,0), Bf11 = LB_(P,1,1), \
           Bf20 = LB_(P,2,0), Bf21 = LB_(P,2,1), Bf30 = LB_(P,3,0), Bf31 = LB_(P,3,1); \
    bf16x8 Aa0 = LA_(P,0,0), Aa1 = LA_(P,0,1), Ab0 = LA_(P,1,0), Ab1 = LA_(P,1,1); \
    if (S1) { G2_(pA1, (Q) * 32768 + 8192); pA1 += 64; } \
    schedb(); sbar(); schedb(); \
    __builtin_amdgcn_s_setprio(1); \
    ROW_(0, Aa0, Aa1); ROW_(1, Ab0, Ab1); \
    __builtin_amdgcn_s_setprio(0); \
    schedb(); sbar(); schedb(); \
    bf16x8 Ac0 = LA_(P,2,0), Ac1 = LA_(P,2,1), Ad0 = LA_(P,3,0), Ad1 = LA_(P,3,1); \
    if (S2) { G2_(pB0, (P) * 32768 + 16384); pB0 += 64; } \
    schedb(); sbar(); schedb(); \
    __builtin_amdgcn_s_setprio(1); \
    ROW_(2, Ac0, Ac1); ROW_(3, Ad0, Ad1); \
    __builtin_amdgcn_s_setprio(0); \
    schedb(); sbar(); schedb(); \
    bf16x8 Ae0 = LA_(P,4,0), Ae1 = LA_(P,4,1), Af0 = LA_(P,5,0), Af1 = LA_(P,5,1), \
           Ag0 = LA_(P,6,0), Ag1 = LA_(P,6,1), Ah0 = LA_(P,7,0), Ah1 = LA_(P,7,1); \
    if (S2) { G2_(pB1, (P) * 32768 + 16384 + 8192); pB1 += 64; } \
    schedb(); sbar(); schedb(); \
    __builtin_amdgcn_s_setprio(1); \
    ROW_(4, Ae0, Ae1); ROW_(5, Af0, Af1); \
    __builtin_amdgcn_s_setprio(0); \
    schedb(); sbar(); schedb(); \
    if (S2) { G2_(pA0, (P) * 32768); pA0 += 64; } \
    if (VM == 6)      { asm volatile("s_waitcnt vmcnt(6)" ::: "memory"); } \
    else if (VM == 0) { asm volatile("s_waitcnt vmcnt(0)" ::: "memory"); } \
    schedb(); sbar(); schedb(); \
    __builtin_amdgcn_s_setprio(1); \
    ROW_(6, Ag0, Ag1); ROW_(7, Ah0, Ah1); \
    __builtin_amdgcn_s_setprio(0); \
    schedb(); sbar(); schedb(); \
  } while (0)

  // ---- prologue: tile0 full -> buf0; tile1 B0,B1,A0 -> buf1 ----
  G2_(gB,               16384);
  G2_(gB + 2 * row64,   16384 + 8192);
  G2_(gA,               0);
  G2_(gA + 2 * row64,   8192);
  asm volatile("s_waitcnt vmcnt(4)" ::: "memory");
  G2_(gB + 64,              32768 + 16384);
  G2_(gB + 2 * row64 + 64,  32768 + 16384 + 8192);
  G2_(gA + 64,              32768);
  asm volatile("s_waitcnt vmcnt(6)" ::: "memory");
  schedb(); sbar(); schedb();

  // running stage pointers (first window t=0 values)
  const u16* pA1 = gA + 2 * row64 + 64;
  const u16* pB0 = gB + 128;
  const u16* pB1 = gB + 2 * row64 + 128;
  const u16* pA0 = gA + 128;

  const int nt = Kk >> 6;  // even (K = 1024 or 4096)
  for (int it = 0; it < (nt - 2) >> 1; ++it) {
    WIN_(0, 1, true, true, 6);
    WIN_(1, 0, true, true, 6);
  }
  WIN_(0, 1, true, false, 0);
  WIN_(1, 0, false, false, -1);

  // ---- epilogue: bias/relu in f32, bf16 -> LDS [256][264], coalesced store ----
  sbar();
  float bvn[4] = {0.f, 0.f, 0.f, 0.f};
  if (EPI == 1) {
    #pragma unroll
    for (int n = 0; n < 4; ++n) bvn[n] = bias[bn + wn * 64 + n * 16 + fr];
  }
  #pragma unroll
  for (int m = 0; m < 8; ++m) {
    #pragma unroll
    for (int n = 0; n < 4; ++n) {
      const int col = wn * 64 + n * 16 + fr;
      #pragma unroll
      for (int j = 0; j < 4; ++j) {
        float v = acc[m][n][j];
        if (EPI == 1) { v += bvn[n]; v = v > 0.f ? v : 0.f; }
        const int row = wm * 128 + m * 16 + (ln >> 4) * 4 + j;
        lds[row * 264 + col] = f2b(v);
      }
    }
  }
  sbar();
  u16* outp = Cb + (size_t)bm * Nn + bn;
  #pragma unroll
  for (int it = 0; it < 16; ++it) {
    const int id = it * 512 + t;
    const int row = id >> 5, colc = (id & 31) * 8;
    u16x8 vv = *(const u16x8*)&lds[row * 264 + colc];
    *(u16x8*)&outp[(size_t)row * Nn + colc] = vv;
  }
#undef WIN_
#undef G2_
#undef LA_
#undef LB_
#undef MM_
#undef ROW_
}

// ---- old 128x128 GEMM, kept only for the final [M,100] output projection ----
__global__ __launch_bounds__(256) void k_gemm_out(const u16* __restrict__ A, const u16* __restrict__ Bt,
                                                  float* __restrict__ Cf, const float* __restrict__ bias,
                                                  int Nn, int Kk) {
  __shared__ __align__(16) u16 As[128 * 32];
  __shared__ __align__(16) u16 Bs[128 * 32];
  const int tid = threadIdx.x;
  const int wv = tid >> 6, ln = tid & 63;
  const int wm = wv >> 1, wn = wv & 1;
  const int bm = blockIdx.y * 128, bn = blockIdx.x * 128;
  f32x4 acc[4][4] = {};

  const int rsub = ln >> 2;
  const int koff = (ln & 3) * 8;
  const int c0 = 2 * wv, c1 = 2 * wv + 1;
  const u16* Ag0 = A + (size_t)(bm + c0 * 16 + rsub) * Kk + koff;
  const u16* Ag1 = A + (size_t)(bm + c1 * 16 + rsub) * Kk + koff;
  const u16* Bg0 = Bt + (size_t)(bn + c0 * 16 + rsub) * Kk + koff;
  const u16* Bg1 = Bt + (size_t)(bn + c1 * 16 + rsub) * Kk + koff;
  u16* As0 = &As[c0 * 512];
  u16* As1 = &As[c1 * 512];
  u16* Bs0 = &Bs[c0 * 512];
  u16* Bs1 = &Bs[c1 * 512];

  const int arow = wm * 64 + (ln & 15);
  const int brow = wn * 64 + (ln & 15);
  const int kfo = (ln >> 4) * 8;

  for (int kt = 0; kt < Kk; kt += 32) {
    GLDS16(Ag0, As0); GLDS16(Ag1, As1);
    GLDS16(Bg0, Bs0); GLDS16(Bg1, Bs1);
    Ag0 += 32; Ag1 += 32; Bg0 += 32; Bg1 += 32;
    __syncthreads();
    bf16x8 af[4], bfr[4];
    #pragma unroll
    for (int m = 0; m < 4; ++m) af[m] = *(const bf16x8*)&As[(arow + m * 16) * 32 + kfo];
    #pragma unroll
    for (int n = 0; n < 4; ++n) bfr[n] = *(const bf16x8*)&Bs[(brow + n * 16) * 32 + kfo];
    #pragma unroll
    for (int m = 0; m < 4; ++m)
      #pragma unroll
      for (int n = 0; n < 4; ++n)
        acc[m][n] = __builtin_amdgcn_mfma_f32_16x16x32_bf16(af[m], bfr[n], acc[m][n], 0, 0, 0);
    __syncthreads();
  }

  #pragma unroll
  for (int m = 0; m < 4; ++m) {
    const int row0 = bm + wm * 64 + m * 16 + (ln >> 4) * 4;
    #pragma unroll
    for (int n = 0; n < 4; ++n) {
      const int col = bn + wn * 64 + n * 16 + (ln & 15);
      #pragma unroll
      for (int j = 0; j < 4; ++j) {
        const int r = row0 + j;
        if (col < TC) {
          const int bb = r >> 11;
          const int sidx = r & (TS - 1);
          Cf[((size_t)sidx * TB + bb) * TC + col] = acc[m][n][j] + bias[col];
        }
      }
    }
  }
}

extern "C" void kernel_launch(void* const* d_in, const int* in_sizes, int n_in,
                              void* d_out, int out_size, void* d_ws, size_t ws_size,
                              hipStream_t stream) {
  (void)in_sizes; (void)n_in; (void)out_size;
  const float* x   = (const float*)d_in[0];
  const float* pos = (const float*)d_in[1];
  const float* cq  = (const float*)d_in[2];
  const float* wq_[2]   = {(const float*)d_in[3],  (const float*)d_in[15]};
  const float* wk_[2]   = {(const float*)d_in[4],  (const float*)d_in[16]};
  const float* wv_[2]   = {(const float*)d_in[5],  (const float*)d_in[17]};
  const float* wo_[2]   = {(const float*)d_in[6],  (const float*)d_in[18]};
  const float* w1_[2]   = {(const float*)d_in[7],  (const float*)d_in[19]};
  const float* b1_[2]   = {(const float*)d_in[8],  (const float*)d_in[20]};
  const float* w2_[2]   = {(const float*)d_in[9],  (const float*)d_in[21]};
  const float* b2_[2]   = {(const float*)d_in[10], (const float*)d_in[22]};
  const float* ln1g_[2] = {(const float*)d_in[11], (const float*)d_in[23]};
  const float* ln1b_[2] = {(const float*)d_in[12], (const float*)d_in[24]};
  const float* ln2g_[2] = {(const float*)d_in[13], (const float*)d_in[25]};
  const float* ln2b_[2] = {(const float*)d_in[14], (const float*)d_in[26]};
  const float* ln3g = (const float*)d_in[27];
  const float* ln3b = (const float*)d_in[28];
  const float* wout = (const float*)d_in[29];
  const float* bout = (const float*)d_in[30];

  char* ws = (char*)d_ws;
  size_t off = 0;
  auto alloc = [&](size_t bytes) {
    void* p = ws + off;
    off = (off + bytes + 255) & ~(size_t)255;
    return p;
  };
  const size_t SZ = (size_t)TM * TD * 2;  // 32 MB bf16 activation buffer
  u16* Hb   = (u16*)alloc(SZ);   // encoder stream (frozen after encoder: decoder K/V source)
  u16* DECb = (u16*)alloc(SZ);   // decoder stream
  u16* Xb   = (u16*)alloc(SZ);   // decoder xd
  u16* Qb   = (u16*)alloc(SZ);   // q / attn-out / ff
  u16* Kb   = (u16*)alloc(SZ);   // k / a
  u16* Vb   = (u16*)alloc(SZ);   // v / h1 / na
  u16* Fb   = (u16*)alloc((size_t)TM * TDFF * 2);    // relu(ff1), 128 MB
  u16* WTq   = (u16*)alloc((size_t)TD * TD * 2);     // WTq..WTo contiguous (tcvt4)
  u16* WTk   = (u16*)alloc((size_t)TD * TD * 2);
  u16* WTv   = (u16*)alloc((size_t)TD * TD * 2);
  u16* WTo   = (u16*)alloc((size_t)TD * TD * 2);
  u16* WT1   = (u16*)alloc((size_t)TDFF * TD * 2);   // [DFF][D]
  u16* WT2   = (u16*)alloc((size_t)TD * TDFF * 2);   // [D][DFF]
  u16* WTout = (u16*)alloc((size_t)128 * TD * 2);    // padded to 128 rows

  if (ws_size < off) return;  // fail-fast cleanly (no OOB) if workspace too small

  const dim3 b256(256);
  const dim3 b512(512);
  const dim3 b328(32, 8);
  const dim3 gElem(TM * TD / 4 / 256);
  const dim3 gLN(TM);
  const dim3 gAttn(TM / 4);
  const dim3 gDD(TD / 256, TM / 256);      // (4, 64)
  const dim3 gFF1(TDFF / 256, TM / 256);   // (16, 64)
  const dim3 gFF2(TD / 256, TM / 256);     // (4, 64)
  const dim3 gT4(TD / 32, TD / 32, 4);
  const dim3 gT_1(TDFF / 32, TD / 32);
  const dim3 gT_2(TD / 32, TDFF / 32);

  k_addpos<<<gElem, b256, 0, stream>>>(x, pos, Hb);

  for (int p = 0; p < 2; ++p) {  // p=0 encoder, p=1 decoder
    if (p == 1) k_decinit<<<gElem, b256, 0, stream>>>(cq, DECb);
    for (int i = 0; i < TL; ++i) {
      const size_t wo_off = (size_t)i * TD * TD;
      k_tcvt4<<<gT4, b328, 0, stream>>>(wq_[p] + wo_off, wk_[p] + wo_off,
                                        wv_[p] + wo_off, wo_[p] + wo_off, WTq);
      k_tcvt<<<gT_1, b328, 0, stream>>>(w1_[p] + (size_t)i * TD * TDFF, WT1, TD, TDFF, TDFF);
      k_tcvt<<<gT_2, b328, 0, stream>>>(w2_[p] + (size_t)i * TDFF * TD, WT2, TDFF, TD, TD);

      if (p == 1)  // xd = LN(dec + dec)
        k_ln<false><<<gLN, b256, 0, stream>>>(DECb, DECb, nullptr,
            ln1g_[1] + (size_t)i * TD, ln1b_[1] + (size_t)i * TD, Xb);

      const u16* qin = (p == 0) ? Hb : DECb;
      const u16* kvin = Hb;
      k_gemm256<0><<<gDD, b512, 0, stream>>>(qin,  WTq, Qb, nullptr, TD, TD);
      k_gemm256<0><<<gDD, b512, 0, stream>>>(kvin, WTk, Kb, nullptr, TD, TD);
      k_gemm256<0><<<gDD, b512, 0, stream>>>(kvin, WTv, Vb, nullptr, TD, TD);
      k_attn<<<gAttn, b256, 0, stream>>>(Qb, Kb, Vb, Qb);  // in-place over Qb
      k_gemm256<0><<<gDD, b512, 0, stream>>>(Qb, WTo, Kb, nullptr, TD, TD);  // a -> Kb

      if (p == 0)  // h1 = LN(h + a) -> Vb
        k_ln<false><<<gLN, b256, 0, stream>>>(Hb, Kb, nullptr,
            ln1g_[0] + (size_t)i * TD, ln1b_[0] + (size_t)i * TD, Vb);
      else         // na = LN(xd + a) -> Vb
        k_ln<false><<<gLN, b256, 0, stream>>>(Xb, Kb, nullptr,
            ln2g_[1] + (size_t)i * TD, ln2b_[1] + (size_t)i * TD, Vb);

      k_gemm256<1><<<gFF1, b512, 0, stream>>>(Vb, WT1, Fb, b1_[p] + (size_t)i * TDFF, TDFF, TD);
      k_gemm256<0><<<gFF2, b512, 0, stream>>>(Fb, WT2, Qb, nullptr, TD, TDFF);  // ff -> Qb

      if (p == 0)  // h = LN(ff + h1 + b2) -> Hb
        k_ln<true><<<gLN, b256, 0, stream>>>(Qb, Vb, b2_[0] + (size_t)i * TD,
            ln2g_[0] + (size_t)i * TD, ln2b_[0] + (size_t)i * TD, Hb);
      else         // dec = LN(na + ff + b2) -> DECb
        k_ln<true><<<gLN, b256, 0, stream>>>(Qb, Vb, b2_[1] + (size_t)i * TD,
            ln3g + (size_t)i * TD, ln3b + (size_t)i * TD, DECb);
    }
  }

  k_tcvt<<<dim3(128 / 32, TD / 32), b328, 0, stream>>>(wout, WTout, TD, TC, 128);
  k_gemm_out<<<dim3(1, TM / 128), b256, 0, stream>>>(DECb, WTout, (float*)d_out, bout, 128, TD);
}

// Round 8
// 6241.798 us; speedup vs baseline: 1.3420x; 1.3420x over previous
//
#include <hip/hip_runtime.h>
#include <hip/hip_bf16.h>
#include <stdint.h>

typedef __bf16 bf16x8 __attribute__((ext_vector_type(8)));
typedef float f32x4 __attribute__((ext_vector_type(4)));
typedef unsigned short u16;
typedef u16 u16x8 __attribute__((ext_vector_type(8)));

static constexpr int TL = 6, TB = 8, TS = 2048, TD = 1024, TDFF = 4096, TC = 100;
static constexpr int TM = TB * TS;  // 16384 tokens

__device__ __forceinline__ u16 f2b(float f) {
  union { float f; uint32_t u; } v; v.f = f;
  return (u16)((v.u + 0x7FFFu + ((v.u >> 16) & 1u)) >> 16);
}
__device__ __forceinline__ float b2f(u16 h) {
  union { uint32_t u; float f; } v; v.u = ((uint32_t)h) << 16;
  return v.f;
}

#define GLDS16(gp, lp) \
  __builtin_amdgcn_global_load_lds((__attribute__((address_space(1))) void*)(gp), \
                                   (__attribute__((address_space(3))) void*)(lp), 16, 0, 0)

__device__ __forceinline__ void sbar() { __builtin_amdgcn_s_barrier(); }
__device__ __forceinline__ void schedb() { __builtin_amdgcn_sched_barrier(0); }

// ---------------- elementwise ----------------
__global__ __launch_bounds__(256) void k_addpos(const float* __restrict__ x, const float* __restrict__ pos,
                                                u16* __restrict__ hb) {
  int idx = blockIdx.x * 256 + threadIdx.x;
  float4 xv = ((const float4*)x)[idx];
  float4 pv = ((const float4*)pos)[idx & (TD / 4 - 1)];
  ushort4 ob;
  ob.x = f2b(xv.x + pv.x); ob.y = f2b(xv.y + pv.y);
  ob.z = f2b(xv.z + pv.z); ob.w = f2b(xv.w + pv.w);
  ((ushort4*)hb)[idx] = ob;
}

__global__ __launch_bounds__(256) void k_decinit(const float* __restrict__ cq, u16* __restrict__ db) {
  int idx = blockIdx.x * 256 + threadIdx.x;
  float4 v = ((const float4*)cq)[idx & (TD / 4 - 1)];
  ushort4 ob; ob.x = f2b(v.x); ob.y = f2b(v.y); ob.z = f2b(v.z); ob.w = f2b(v.w);
  ((ushort4*)db)[idx] = ob;
}

// transpose + convert: W [K,N] f32 -> Wt [Npad,K] bf16 (rows N..Npad zero-filled)
__global__ void k_tcvt(const float* __restrict__ W, u16* __restrict__ Wt, int K, int N, int Npad) {
  __shared__ float tile[32][33];
  int bn = blockIdx.x * 32, bk = blockIdx.y * 32;
  int tx = threadIdx.x, ty = threadIdx.y;  // 32x8
  #pragma unroll
  for (int i = ty; i < 32; i += 8) {
    int k = bk + i, n = bn + tx;
    tile[i][tx] = (k < K && n < N) ? W[(size_t)k * N + n] : 0.f;
  }
  __syncthreads();
  #pragma unroll
  for (int i = ty; i < 32; i += 8) {
    int n = bn + i, k = bk + tx;
    if (n < Npad && k < K) Wt[(size_t)n * K + k] = (n < N) ? f2b(tile[tx][i]) : (u16)0;
  }
}

// merged transpose+convert for the four [D,D] attention weights (z = which)
__global__ void k_tcvt4(const float* __restrict__ w0, const float* __restrict__ w1,
                        const float* __restrict__ w2, const float* __restrict__ w3,
                        u16* __restrict__ Wt) {
  __shared__ float tile[32][33];
  const float* W = (blockIdx.z == 0) ? w0 : (blockIdx.z == 1) ? w1 : (blockIdx.z == 2) ? w2 : w3;
  u16* O = Wt + (size_t)blockIdx.z * TD * TD;
  int bn = blockIdx.x * 32, bk = blockIdx.y * 32;
  int tx = threadIdx.x, ty = threadIdx.y;  // 32x8
  #pragma unroll
  for (int i = ty; i < 32; i += 8) tile[i][tx] = W[(size_t)(bk + i) * TD + bn + tx];
  __syncthreads();
  #pragma unroll
  for (int i = ty; i < 32; i += 8) O[(size_t)(bn + i) * TD + bk + tx] = f2b(tile[tx][i]);
}

// LayerNorm over D=1024: out = LN(a + b (+ bias)) * g + be ; bf16 in, bf16 out
template<bool HAS_BIAS>
__global__ __launch_bounds__(256) void k_ln(const u16* __restrict__ a, const u16* __restrict__ b,
                                            const float* __restrict__ bias,
                                            const float* __restrict__ g, const float* __restrict__ be,
                                            u16* __restrict__ outb) {
  int row = blockIdx.x, t = threadIdx.x;
  size_t base = (size_t)row * TD;
  ushort4 av = ((const ushort4*)(a + base))[t];
  ushort4 bv = ((const ushort4*)(b + base))[t];
  float xv[4];
  xv[0] = b2f(av.x) + b2f(bv.x);
  xv[1] = b2f(av.y) + b2f(bv.y);
  xv[2] = b2f(av.z) + b2f(bv.z);
  xv[3] = b2f(av.w) + b2f(bv.w);
  if (HAS_BIAS) {
    float4 bb = ((const float4*)bias)[t];
    xv[0] += bb.x; xv[1] += bb.y; xv[2] += bb.z; xv[3] += bb.w;
  }
  float s = xv[0] + xv[1] + xv[2] + xv[3];
  float q = xv[0] * xv[0] + xv[1] * xv[1] + xv[2] * xv[2] + xv[3] * xv[3];
  #pragma unroll
  for (int o = 32; o > 0; o >>= 1) { s += __shfl_down(s, o); q += __shfl_down(q, o); }
  __shared__ float ss[4], qs_[4];
  int wv = t >> 6;
  if ((t & 63) == 0) { ss[wv] = s; qs_[wv] = q; }
  __syncthreads();
  s = ss[0] + ss[1] + ss[2] + ss[3];
  q = qs_[0] + qs_[1] + qs_[2] + qs_[3];
  float m = s * (1.f / TD);
  float rs = rsqrtf(q * (1.f / TD) - m * m + 1e-5f);
  float4 gv = ((const float4*)g)[t];
  float4 bev = ((const float4*)be)[t];
  ushort4 ob;
  ob.x = f2b((xv[0] - m) * rs * gv.x + bev.x);
  ob.y = f2b((xv[1] - m) * rs * gv.y + bev.y);
  ob.z = f2b((xv[2] - m) * rs * gv.z + bev.z);
  ob.w = f2b((xv[3] - m) * rs * gv.w + bev.w);
  ((ushort4*)(outb + base))[t] = ob;
}

// per-token 16x16 head-mix "attention": one wave per token. Ob may alias Qb.
__global__ __launch_bounds__(256) void k_attn(const u16* __restrict__ Qb, const u16* __restrict__ Kb,
                                              const u16* __restrict__ Vb, u16* __restrict__ Ob) {
  constexpr int ST = 72;  // padded row stride (floats)
  __shared__ float sh[4][3][16 * ST];
  __shared__ float ps[4][16 * 17];
  const int wv = threadIdx.x >> 6, ln = threadIdx.x & 63;
  const size_t base = ((size_t)blockIdx.x * 4 + wv) * TD;
  float* qs = sh[wv][0];
  float* ks = sh[wv][1];
  float* vs = sh[wv][2];
  #pragma unroll
  for (int it = 0; it < 4; ++it) {
    const int e = it * 256 + ln * 4;
    const int li = (e >> 6) * ST + (e & 63);
    ushort4 qv = *(const ushort4*)(Qb + base + e);
    ushort4 kv = *(const ushort4*)(Kb + base + e);
    ushort4 vv = *(const ushort4*)(Vb + base + e);
    *(float4*)(qs + li) = make_float4(b2f(qv.x), b2f(qv.y), b2f(qv.z), b2f(qv.w));
    *(float4*)(ks + li) = make_float4(b2f(kv.x), b2f(kv.y), b2f(kv.z), b2f(kv.w));
    *(float4*)(vs + li) = make_float4(b2f(vv.x), b2f(vv.y), b2f(vv.z), b2f(vv.w));
  }
  __syncthreads();
  const int hi = ln >> 2, jg = ln & 3;
  float sc[4] = {0.f, 0.f, 0.f, 0.f};
  for (int d = 0; d < 64; ++d) {
    const float qv = qs[hi * ST + d];
    #pragma unroll
    for (int jj = 0; jj < 4; ++jj) sc[jj] += qv * ks[(jg * 4 + jj) * ST + d];
  }
  #pragma unroll
  for (int jj = 0; jj < 4; ++jj) sc[jj] *= 0.125f;  // 1/sqrt(64)
  float mx = fmaxf(fmaxf(sc[0], sc[1]), fmaxf(sc[2], sc[3]));
  mx = fmaxf(mx, __shfl_xor(mx, 1, 4));
  mx = fmaxf(mx, __shfl_xor(mx, 2, 4));
  float sum = 0.f;
  #pragma unroll
  for (int jj = 0; jj < 4; ++jj) { sc[jj] = __expf(sc[jj] - mx); sum += sc[jj]; }
  sum += __shfl_xor(sum, 1, 4);
  sum += __shfl_xor(sum, 2, 4);
  const float inv = 1.f / sum;
  #pragma unroll
  for (int jj = 0; jj < 4; ++jj) ps[wv][hi * 17 + jg * 4 + jj] = sc[jj] * inv;
  __syncthreads();
  float out[16];
  #pragma unroll
  for (int t = 0; t < 16; ++t) out[t] = 0.f;
  #pragma unroll
  for (int j = 0; j < 16; ++j) {
    const float pij = ps[wv][hi * 17 + j];
    #pragma unroll
    for (int t = 0; t < 16; ++t) out[t] += pij * vs[j * ST + jg * 16 + t];
  }
  u16* op = Ob + base + hi * 64 + jg * 16;
  #pragma unroll
  for (int t4 = 0; t4 < 4; ++t4) {
    ushort4 ob;
    ob.x = f2b(out[t4 * 4 + 0]); ob.y = f2b(out[t4 * 4 + 1]);
    ob.z = f2b(out[t4 * 4 + 2]); ob.w = f2b(out[t4 * 4 + 3]);
    *(ushort4*)(op + t4 * 4) = ob;
  }
}

// ============ 256x256 8-phase pipelined GEMM — EXACT round-3 structure + T1 swizzle ============
// (Round-3 lambda-window/runtime-parity form measured 6399us total vs 7572-8391 for the
//  static-parity rewrite; reverted. Single new lever: XCD-aware bijective block swizzle.)
// C[M,Nn](bf16) = A[M,Kk](bf16) @ Bt[Nn,Kk](bf16)^T.  BK=64, 8 waves (2Mx4N),
// 128KB dbuf LDS, granule swizzle elem^=(row&7)<<3 on stage-source AND ds_read,
// counted vmcnt(6) once per K-tile, raw barriers, setprio around MFMA.
// EPI 0: bf16 store. EPI 1: bias+relu -> bf16 store.
template<int EPI>
__global__ __launch_bounds__(512, 2) void k_gemm256(const u16* __restrict__ A, const u16* __restrict__ Bt,
                                                    u16* __restrict__ Cb, const float* __restrict__ bias,
                                                    int Nn, int Kk) {
  __shared__ __align__(16) u16 lds[67584];
  const int t = threadIdx.x;
  const int wv = t >> 6, ln = t & 63;
  const int wm = wv >> 2, wn = wv & 3;

  // ---- T1: XCD-aware bijective swizzle (all grids have nwg % 8 == 0).
  // XCD x owns a contiguous row-major chunk of tiles -> A-panel lives in ONE L2.
  const int nwgx = gridDim.x;
  const int nwg = nwgx * gridDim.y;
  const int orig = blockIdx.y * nwgx + blockIdx.x;
  const int swz = (orig & 7) * (nwg >> 3) + (orig >> 3);
  const int by = swz / nwgx;
  const int bx = swz - by * nwgx;
  const int bm = by * 256, bn = bx * 256;

  // staging: thread covers rows j*64+(t>>3) of a 128-row half, 8 cols from (t&7)*8
  const int srow = t >> 3;
  const int ssc = ((t & 7) * 8) ^ ((srow & 7) << 3);  // pre-swizzled source col
  // fragment reads
  const int fr = ln & 15;
  const int fk = (ln >> 4) * 8;
  const int fperm = (fr & 7) << 3;
  const int kc0 = fk ^ fperm;
  const int kc1 = (32 + fk) ^ fperm;
  const int arow = (wm * 128 + fr) * 64;
  const int brow = (wn * 64 + fr) * 64;

  f32x4 acc[8][4] = {};

  auto stage = [&](const u16* __restrict__ G, int half, int grow0, int kcol, int sec) {
    #pragma unroll
    for (int j = 0; j < 2; ++j) {
      const u16* gp = G + (size_t)(grow0 + half * 128 + j * 64 + srow) * Kk + kcol + ssc;
      const u16* lp = &lds[sec + half * 8192 + j * 4096 + wv * 512];
      GLDS16(gp, lp);
    }
  };

#define LA_(buf, m, ks) (*(const bf16x8*)&lds[(buf) * 32768 + arow + (m) * 1024 + ((ks) ? kc1 : kc0)])
#define LB_(buf, n, ks) (*(const bf16x8*)&lds[(buf) * 32768 + 16384 + brow + (n) * 1024 + ((ks) ? kc1 : kc0)])
#define MM_(a, b, c) __builtin_amdgcn_mfma_f32_16x16x32_bf16(a, b, c, 0, 0, 0)
#define ROW_(m, X0, X1) \
  acc[m][0] = MM_(X0, Bf00, acc[m][0]); acc[m][0] = MM_(X1, Bf01, acc[m][0]); \
  acc[m][1] = MM_(X0, Bf10, acc[m][1]); acc[m][1] = MM_(X1, Bf11, acc[m][1]); \
  acc[m][2] = MM_(X0, Bf20, acc[m][2]); acc[m][2] = MM_(X1, Bf21, acc[m][2]); \
  acc[m][3] = MM_(X0, Bf30, acc[m][3]); acc[m][3] = MM_(X1, Bf31, acc[m][3]);

  auto window = [&](int kt, int p, bool s1, bool s2, int vm) {
    const int q = p ^ 1;
    // ---- phase 1: read all B + A m0-1; stage (t+1).A1 -> buf q ----
    bf16x8 Bf00 = LB_(p, 0, 0), Bf01 = LB_(p, 0, 1), Bf10 = LB_(p, 1, 0), Bf11 = LB_(p, 1, 1),
           Bf20 = LB_(p, 2, 0), Bf21 = LB_(p, 2, 1), Bf30 = LB_(p, 3, 0), Bf31 = LB_(p, 3, 1);
    bf16x8 Aa0 = LA_(p, 0, 0), Aa1 = LA_(p, 0, 1), Ab0 = LA_(p, 1, 0), Ab1 = LA_(p, 1, 1);
    if (s1) stage(A, 1, bm, kt + 64, q * 32768);
    schedb(); sbar(); schedb();
    __builtin_amdgcn_s_setprio(1);
    ROW_(0, Aa0, Aa1); ROW_(1, Ab0, Ab1);
    __builtin_amdgcn_s_setprio(0);
    schedb(); sbar(); schedb();
    // ---- phase 2: read A m2-3; stage (t+2).B0 -> buf p ----
    bf16x8 Ac0 = LA_(p, 2, 0), Ac1 = LA_(p, 2, 1), Ad0 = LA_(p, 3, 0), Ad1 = LA_(p, 3, 1);
    if (s2) stage(Bt, 0, bn, kt + 128, p * 32768 + 16384);
    schedb(); sbar(); schedb();
    __builtin_amdgcn_s_setprio(1);
    ROW_(2, Ac0, Ac1); ROW_(3, Ad0, Ad1);
    __builtin_amdgcn_s_setprio(0);
    schedb(); sbar(); schedb();
    // ---- phase 3: read A m4-7; stage (t+2).B1 -> buf p ----
    bf16x8 Ae0 = LA_(p, 4, 0), Ae1 = LA_(p, 4, 1), Af0 = LA_(p, 5, 0), Af1 = LA_(p, 5, 1),
           Ag0 = LA_(p, 6, 0), Ag1 = LA_(p, 6, 1), Ah0 = LA_(p, 7, 0), Ah1 = LA_(p, 7, 1);
    if (s2) stage(Bt, 1, bn, kt + 128, p * 32768 + 16384);
    schedb(); sbar(); schedb();
    __builtin_amdgcn_s_setprio(1);
    ROW_(4, Ae0, Ae1); ROW_(5, Af0, Af1);
    __builtin_amdgcn_s_setprio(0);
    schedb(); sbar(); schedb();
    // ---- phase 4: stage (t+2).A0 -> buf p; counted vmcnt ----
    if (s2) stage(A, 0, bm, kt + 128, p * 32768);
    if (vm == 6)      { asm volatile("s_waitcnt vmcnt(6)" ::: "memory"); }
    else if (vm == 0) { asm volatile("s_waitcnt vmcnt(0)" ::: "memory"); }
    schedb(); sbar(); schedb();
    __builtin_amdgcn_s_setprio(1);
    ROW_(6, Ag0, Ag1); ROW_(7, Ah0, Ah1);
    __builtin_amdgcn_s_setprio(0);
    schedb(); sbar(); schedb();
  };

  // ---- prologue: t0 full -> buf0; t1.B0,B1,A0 -> buf1 ----
  stage(Bt, 0, bn, 0, 16384);
  stage(Bt, 1, bn, 0, 16384);
  stage(A,  0, bm, 0, 0);
  stage(A,  1, bm, 0, 0);
  asm volatile("s_waitcnt vmcnt(4)" ::: "memory");
  stage(Bt, 0, bn, 64, 32768 + 16384);
  stage(Bt, 1, bn, 64, 32768 + 16384);
  stage(A,  0, bm, 64, 32768);
  asm volatile("s_waitcnt vmcnt(6)" ::: "memory");
  schedb(); sbar(); schedb();

  const int nt = Kk >> 6;
  for (int tt = 0; tt < nt - 2; ++tt)
    window(tt * 64, tt & 1, true, true, 6);
  window((nt - 2) * 64, (nt - 2) & 1, true, false, 0);
  window((nt - 1) * 64, (nt - 1) & 1, false, false, -1);

  // ---- epilogue: bias/relu in f32, bf16 -> LDS [256][264], coalesced store ----
  sbar();
  float bvn[4] = {0.f, 0.f, 0.f, 0.f};
  if (EPI == 1) {
    #pragma unroll
    for (int n = 0; n < 4; ++n) bvn[n] = bias[bn + wn * 64 + n * 16 + fr];
  }
  #pragma unroll
  for (int m = 0; m < 8; ++m) {
    #pragma unroll
    for (int n = 0; n < 4; ++n) {
      const int col = wn * 64 + n * 16 + fr;
      #pragma unroll
      for (int j = 0; j < 4; ++j) {
        float v = acc[m][n][j];
        if (EPI == 1) { v += bvn[n]; v = v > 0.f ? v : 0.f; }
        const int row = wm * 128 + m * 16 + (ln >> 4) * 4 + j;
        lds[row * 264 + col] = f2b(v);
      }
    }
  }
  sbar();
  #pragma unroll
  for (int it = 0; it < 16; ++it) {
    const int id = it * 512 + t;
    const int row = id >> 5, colc = (id & 31) * 8;
    u16x8 vv = *(const u16x8*)&lds[row * 264 + colc];
    *(u16x8*)&Cb[(size_t)(bm + row) * Nn + bn + colc] = vv;
  }
#undef LA_
#undef LB_
#undef MM_
#undef ROW_
}

// ---- old 128x128 GEMM, kept only for the final [M,100] output projection ----
__global__ __launch_bounds__(256) void k_gemm_out(const u16* __restrict__ A, const u16* __restrict__ Bt,
                                                  float* __restrict__ Cf, const float* __restrict__ bias,
                                                  int Nn, int Kk) {
  __shared__ __align__(16) u16 As[128 * 32];
  __shared__ __align__(16) u16 Bs[128 * 32];
  const int tid = threadIdx.x;
  const int wv = tid >> 6, ln = tid & 63;
  const int wm = wv >> 1, wn = wv & 1;
  const int bm = blockIdx.y * 128, bn = blockIdx.x * 128;
  f32x4 acc[4][4] = {};

  const int rsub = ln >> 2;
  const int koff = (ln & 3) * 8;
  const int c0 = 2 * wv, c1 = 2 * wv + 1;
  const u16* Ag0 = A + (size_t)(bm + c0 * 16 + rsub) * Kk + koff;
  const u16* Ag1 = A + (size_t)(bm + c1 * 16 + rsub) * Kk + koff;
  const u16* Bg0 = Bt + (size_t)(bn + c0 * 16 + rsub) * Kk + koff;
  const u16* Bg1 = Bt + (size_t)(bn + c1 * 16 + rsub) * Kk + koff;
  u16* As0 = &As[c0 * 512];
  u16* As1 = &As[c1 * 512];
  u16* Bs0 = &Bs[c0 * 512];
  u16* Bs1 = &Bs[c1 * 512];

  const int arow = wm * 64 + (ln & 15);
  const int brow = wn * 64 + (ln & 15);
  const int kfo = (ln >> 4) * 8;

  for (int kt = 0; kt < Kk; kt += 32) {
    GLDS16(Ag0, As0); GLDS16(Ag1, As1);
    GLDS16(Bg0, Bs0); GLDS16(Bg1, Bs1);
    Ag0 += 32; Ag1 += 32; Bg0 += 32; Bg1 += 32;
    __syncthreads();
    bf16x8 af[4], bfr[4];
    #pragma unroll
    for (int m = 0; m < 4; ++m) af[m] = *(const bf16x8*)&As[(arow + m * 16) * 32 + kfo];
    #pragma unroll
    for (int n = 0; n < 4; ++n) bfr[n] = *(const bf16x8*)&Bs[(brow + n * 16) * 32 + kfo];
    #pragma unroll
    for (int m = 0; m < 4; ++m)
      #pragma unroll
      for (int n = 0; n < 4; ++n)
        acc[m][n] = __builtin_amdgcn_mfma_f32_16x16x32_bf16(af[m], bfr[n], acc[m][n], 0, 0, 0);
    __syncthreads();
  }

  #pragma unroll
  for (int m = 0; m < 4; ++m) {
    const int row0 = bm + wm * 64 + m * 16 + (ln >> 4) * 4;
    #pragma unroll
    for (int n = 0; n < 4; ++n) {
      const int col = bn + wn * 64 + n * 16 + (ln & 15);
      #pragma unroll
      for (int j = 0; j < 4; ++j) {
        const int r = row0 + j;
        if (col < TC) {
          const int bb = r >> 11;
          const int sidx = r & (TS - 1);
          Cf[((size_t)sidx * TB + bb) * TC + col] = acc[m][n][j] + bias[col];
        }
      }
    }
  }
}

extern "C" void kernel_launch(void* const* d_in, const int* in_sizes, int n_in,
                              void* d_out, int out_size, void* d_ws, size_t ws_size,
                              hipStream_t stream) {
  (void)in_sizes; (void)n_in; (void)out_size;
  const float* x   = (const float*)d_in[0];
  const float* pos = (const float*)d_in[1];
  const float* cq  = (const float*)d_in[2];
  const float* wq_[2]   = {(const float*)d_in[3],  (const float*)d_in[15]};
  const float* wk_[2]   = {(const float*)d_in[4],  (const float*)d_in[16]};
  const float* wv_[2]   = {(const float*)d_in[5],  (const float*)d_in[17]};
  const float* wo_[2]   = {(const float*)d_in[6],  (const float*)d_in[18]};
  const float* w1_[2]   = {(const float*)d_in[7],  (const float*)d_in[19]};
  const float* b1_[2]   = {(const float*)d_in[8],  (const float*)d_in[20]};
  const float* w2_[2]   = {(const float*)d_in[9],  (const float*)d_in[21]};
  const float* b2_[2]   = {(const float*)d_in[10], (const float*)d_in[22]};
  const float* ln1g_[2] = {(const float*)d_in[11], (const float*)d_in[23]};
  const float* ln1b_[2] = {(const float*)d_in[12], (const float*)d_in[24]};
  const float* ln2g_[2] = {(const float*)d_in[13], (const float*)d_in[25]};
  const float* ln2b_[2] = {(const float*)d_in[14], (const float*)d_in[26]};
  const float* ln3g = (const float*)d_in[27];
  const float* ln3b = (const float*)d_in[28];
  const float* wout = (const float*)d_in[29];
  const float* bout = (const float*)d_in[30];

  char* ws = (char*)d_ws;
  size_t off = 0;
  auto alloc = [&](size_t bytes) {
    void* p = ws + off;
    off = (off + bytes + 255) & ~(size_t)255;
    return p;
  };
  const size_t SZ = (size_t)TM * TD * 2;  // 32 MB bf16 activation buffer
  u16* Hb   = (u16*)alloc(SZ);   // encoder stream (frozen after encoder: decoder K/V source)
  u16* DECb = (u16*)alloc(SZ);   // decoder stream
  u16* Xb   = (u16*)alloc(SZ);   // decoder xd
  u16* Qb   = (u16*)alloc(SZ);   // q / attn-out / ff
  u16* Kb   = (u16*)alloc(SZ);   // k / a
  u16* Vb   = (u16*)alloc(SZ);   // v / h1 / na
  u16* Fb   = (u16*)alloc((size_t)TM * TDFF * 2);    // relu(ff1), 128 MB
  u16* WTq   = (u16*)alloc((size_t)TD * TD * 2);     // WTq..WTo contiguous (tcvt4)
  u16* WTk   = (u16*)alloc((size_t)TD * TD * 2);
  u16* WTv   = (u16*)alloc((size_t)TD * TD * 2);
  u16* WTo   = (u16*)alloc((size_t)TD * TD * 2);
  u16* WT1   = (u16*)alloc((size_t)TDFF * TD * 2);   // [DFF][D]
  u16* WT2   = (u16*)alloc((size_t)TD * TDFF * 2);   // [D][DFF]
  u16* WTout = (u16*)alloc((size_t)128 * TD * 2);    // padded to 128 rows

  if (ws_size < off) return;  // fail-fast cleanly (no OOB) if workspace too small

  const dim3 b256(256);
  const dim3 b512(512);
  const dim3 b328(32, 8);
  const dim3 gElem(TM * TD / 4 / 256);
  const dim3 gLN(TM);
  const dim3 gAttn(TM / 4);
  const dim3 gDD(TD / 256, TM / 256);      // (4, 64)
  const dim3 gFF1(TDFF / 256, TM / 256);   // (16, 64)
  const dim3 gFF2(TD / 256, TM / 256);     // (4, 64)
  const dim3 gT4(TD / 32, TD / 32, 4);
  const dim3 gT_1(TDFF / 32, TD / 32);
  const dim3 gT_2(TD / 32, TDFF / 32);

  k_addpos<<<gElem, b256, 0, stream>>>(x, pos, Hb);

  for (int p = 0; p < 2; ++p) {  // p=0 encoder, p=1 decoder
    if (p == 1) k_decinit<<<gElem, b256, 0, stream>>>(cq, DECb);
    for (int i = 0; i < TL; ++i) {
      const size_t wo_off = (size_t)i * TD * TD;
      k_tcvt4<<<gT4, b328, 0, stream>>>(wq_[p] + wo_off, wk_[p] + wo_off,
                                        wv_[p] + wo_off, wo_[p] + wo_off, WTq);
      k_tcvt<<<gT_1, b328, 0, stream>>>(w1_[p] + (size_t)i * TD * TDFF, WT1, TD, TDFF, TDFF);
      k_tcvt<<<gT_2, b328, 0, stream>>>(w2_[p] + (size_t)i * TDFF * TD, WT2, TDFF, TD, TD);

      if (p == 1)  // xd = LN(dec + dec)
        k_ln<false><<<gLN, b256, 0, stream>>>(DECb, DECb, nullptr,
            ln1g_[1] + (size_t)i * TD, ln1b_[1] + (size_t)i * TD, Xb);

      const u16* qin = (p == 0) ? Hb : DECb;
      const u16* kvin = Hb;
      k_gemm256<0><<<gDD, b512, 0, stream>>>(qin,  WTq, Qb, nullptr, TD, TD);
      k_gemm256<0><<<gDD, b512, 0, stream>>>(kvin, WTk, Kb, nullptr, TD, TD);
      k_gemm256<0><<<gDD, b512, 0, stream>>>(kvin, WTv, Vb, nullptr, TD, TD);
      k_attn<<<gAttn, b256, 0, stream>>>(Qb, Kb, Vb, Qb);  // in-place over Qb
      k_gemm256<0><<<gDD, b512, 0, stream>>>(Qb, WTo, Kb, nullptr, TD, TD);  // a -> Kb

      if (p == 0)  // h1 = LN(h + a) -> Vb
        k_ln<false><<<gLN, b256, 0, stream>>>(Hb, Kb, nullptr,
            ln1g_[0] + (size_t)i * TD, ln1b_[0] + (size_t)i * TD, Vb);
      else         // na = LN(xd + a) -> Vb
        k_ln<false><<<gLN, b256, 0, stream>>>(Xb, Kb, nullptr,
            ln2g_[1] + (size_t)i * TD, ln2b_[1] + (size_t)i * TD, Vb);

      k_gemm256<1><<<gFF1, b512, 0, stream>>>(Vb, WT1, Fb, b1_[p] + (size_t)i * TDFF, TDFF, TD);
      k_gemm256<0><<<gFF2, b512, 0, stream>>>(Fb, WT2, Qb, nullptr, TD, TDFF);  // ff -> Qb

      if (p == 0)  // h = LN(ff + h1 + b2) -> Hb
        k_ln<true><<<gLN, b256, 0, stream>>>(Qb, Vb, b2_[0] + (size_t)i * TD,
            ln2g_[0] + (size_t)i * TD, ln2b_[0] + (size_t)i * TD, Hb);
      else         // dec = LN(na + ff + b2) -> DECb
        k_ln<true><<<gLN, b256, 0, stream>>>(Qb, Vb, b2_[1] + (size_t)i * TD,
            ln3g + (size_t)i * TD, ln3b + (size_t)i * TD, DECb);
    }
  }

  k_tcvt<<<dim3(128 / 32, TD / 32), b328, 0, stream>>>(wout, WTout, TD, TC, 128);
  k_gemm_out<<<dim3(1, TM / 128), b256, 0, stream>>>(DECb, WTout, (float*)d_out, bout, 128, TD);
}